// Round 1
// 504.836 us; speedup vs baseline: 1.1695x; 1.1695x over previous
//
#include <hip/hip_runtime.h>
#include <math.h>

#define BSZ 256
#define DIM 1024
#define VOC 50257
#define NL 2
#define NB 8
#define DH 128

typedef __bf16 bf16x8 __attribute__((ext_vector_type(8)));
typedef float  f32x4  __attribute__((ext_vector_type(4)));
typedef unsigned short u16;
typedef u16 u16x8 __attribute__((ext_vector_type(8)));

__device__ __forceinline__ u16 f2bf(float f) {
  unsigned int u = __float_as_uint(f);
  u += 0x7fffu + ((u >> 16) & 1u);   // RNE
  return (u16)(u >> 16);
}
__device__ __forceinline__ float sigm(float x) { return 1.0f / (1.0f + __expf(-x)); }

// ---------------------------------------------------------------------------
// Barrier-free per-wave GEMM: acc[M16][N16] += A(bf16, row-major lda) *
// B(fp32, row-major ldb)^T. Fragments loaded directly from global in MFMA
// operand layout; peeled 2-stage register double-buffer (no LDS, no barriers).
// (Used by the small GEMMs; k_logits has its own LDS-staged pipeline.)
// ---------------------------------------------------------------------------
template<int M16, int N16, int K, bool CLAMPN>
__device__ __forceinline__ void wave_gemm(
    const u16* __restrict__ A, int lda,
    const float* __restrict__ B, int ldb, int nClamp,
    f32x4 (&acc)[M16][N16])
{
  const int lane = threadIdx.x & 63;
  const int quad = lane >> 4;
  const int l16  = lane & 15;

  const u16* aR[M16];
  const float* bR[N16];
#pragma unroll
  for (int mi = 0; mi < M16; ++mi)
    aR[mi] = A + (long)(mi * 16 + l16) * lda + quad * 8;
#pragma unroll
  for (int ni = 0; ni < N16; ++ni) {
    int n = ni * 16 + l16;
    if (CLAMPN) n = n > nClamp ? nClamp : n;   // clamp addr; result discarded
    bR[ni] = B + (long)n * ldb + quad * 8;
  }

  bf16x8 aF[2][M16];
  bf16x8 bF[2][N16];

#define WG_LOAD(kk, buf)                                                  \
  {                                                                       \
    _Pragma("unroll")                                                     \
    for (int ni = 0; ni < N16; ++ni) {                                    \
      float4 v0 = *(const float4*)(bR[ni] + (kk));                        \
      float4 v1 = *(const float4*)(bR[ni] + (kk) + 4);                    \
      u16x8 h;                                                            \
      h[0] = f2bf(v0.x); h[1] = f2bf(v0.y);                               \
      h[2] = f2bf(v0.z); h[3] = f2bf(v0.w);                               \
      h[4] = f2bf(v1.x); h[5] = f2bf(v1.y);                               \
      h[6] = f2bf(v1.z); h[7] = f2bf(v1.w);                               \
      bF[buf][ni] = __builtin_bit_cast(bf16x8, h);                        \
    }                                                                     \
    _Pragma("unroll")                                                     \
    for (int mi = 0; mi < M16; ++mi)                                      \
      aF[buf][mi] = *(const bf16x8*)(aR[mi] + (kk));                      \
  }

#define WG_MM(buf)                                                        \
  {                                                                       \
    _Pragma("unroll")                                                     \
    for (int mi = 0; mi < M16; ++mi)                                      \
      _Pragma("unroll")                                                   \
      for (int ni = 0; ni < N16; ++ni)                                    \
        acc[mi][ni] = __builtin_amdgcn_mfma_f32_16x16x32_bf16(            \
            aF[buf][mi], bF[buf][ni], acc[mi][ni], 0, 0, 0);              \
  }

  WG_LOAD(0, 0);
#pragma unroll 1
  for (int kk = 0; kk < K - 64; kk += 64) {
    WG_LOAD(kk + 32, 1);
    WG_MM(0);
    WG_LOAD(kk + 64, 0);
    WG_MM(1);
  }
  WG_LOAD(K - 32, 1);
  WG_MM(0);
  WG_MM(1);
#undef WG_LOAD
#undef WG_MM
}

#define ACC_DECL(N16V)                                \
  f32x4 acc[4][N16V];                                 \
  { f32x4 z = {0.f, 0.f, 0.f, 0.f};                   \
    _Pragma("unroll")                                 \
    for (int i = 0; i < 4; ++i)                       \
      _Pragma("unroll")                               \
      for (int j = 0; j < N16V; ++j) acc[i][j] = z; }

// ---------------------------------------------------------------------------
// K1: carry (bool-layout detect), x gather, h->bf16, + LLC warm of all weights
// ---------------------------------------------------------------------------
__global__ __launch_bounds__(256) void k_prep(
    const int* __restrict__ ids, const void* __restrict__ mask,
    const float* __restrict__ emb, const float* __restrict__ hstate,
    const float* __restrict__ W_alpha, const float* __restrict__ W_in,
    const float* __restrict__ W_wm_out, const float* __restrict__ W_x,
    const float* __restrict__ W_h, const float* __restrict__ W_wml,
    const float* __restrict__ W_g,
    float* __restrict__ xout, u16* __restrict__ x_bf,
    u16* __restrict__ h_bf, float* __restrict__ carry, float* __restrict__ sink)
{
  __shared__ int sInt;
  const int tid = threadIdx.x, s = blockIdx.x;
  if (tid == 0) sInt = 1;
  __syncthreads();
  if (tid < 64) {
    int v = ((const int*)mask)[tid];
    if (v != 0 && v != 1) atomicAnd(&sInt, 0);
  }
  __syncthreads();
  if (tid == 0) {
    int m = sInt ? ((const int*)mask)[s] : (int)((const unsigned char*)mask)[s];
    carry[s] = m ? 0.0f : 1.0f;
  }
  long id = ids[s];
  int k = tid * 4;
  float4 v = *(const float4*)(emb + id * DIM + k);
  *(float4*)(xout + (long)s * DIM + k) = v;
  ushort4 h; h.x = f2bf(v.x); h.y = f2bf(v.y); h.z = f2bf(v.z); h.w = f2bf(v.w);
  *(ushort4*)(x_bf + (long)s * DIM + k) = h;
#pragma unroll
  for (int l = 0; l < NL; ++l) {
    long off = (long)l * BSZ * DIM + (long)s * DIM + k;
    float4 w = *(const float4*)(hstate + off);
    ushort4 o; o.x = f2bf(w.x); o.y = f2bf(w.y); o.z = f2bf(w.z); o.w = f2bf(w.w);
    *(ushort4*)(h_bf + off) = o;
  }
  // ---- LLC warm (loads can't be eliminated; branch never taken) ----
  long gtid = (long)blockIdx.x * 256 + tid;
  long gstride = (long)gridDim.x * 256;
  float acc = 0.f;
  {
    const long nDD = (long)DIM * DIM / 4;       // 1024x1024 f32 -> float4 count
    for (long i = gtid; i < nDD; i += gstride) {
      float4 a = ((const float4*)W_alpha)[i];
      float4 b = ((const float4*)W_in)[i];
      float4 c = ((const float4*)W_wm_out)[i];
      acc += a.x + a.w + b.x + b.w + c.x + c.w;
    }
    const long nS = (long)NL * NB * DH * DH / 4;
    for (long i = gtid; i < nS; i += gstride) {
      float4 a = ((const float4*)W_x)[i];
      float4 b = ((const float4*)W_h)[i];
      float4 c = ((const float4*)W_g)[i];
      acc += a.x + a.w + b.x + b.w + c.x + c.w;
    }
    const long nW = (long)NL * NB * DH * DIM / 4;
    for (long i = gtid; i < nW; i += gstride) {
      float4 a = ((const float4*)W_wml)[i];
      acc += a.x + a.w;
    }
  }
  if (acc == -1.17521e35f) *sink = acc;   // never true in practice; defeats DCE
}

// ---------------------------------------------------------------------------
// K2: [alpha_pre | x_proj] = x @ [W_alpha ; W_in]^T, fused wm_new epilogue
// 512 blocks x 64 threads: m-slice = blk&3, n-tile16 = blk>>2 (128 tiles)
// ---------------------------------------------------------------------------
__global__ __launch_bounds__(64) void k_gemm1(
    const u16* __restrict__ x_bf,
    const float* __restrict__ W_alpha, const float* __restrict__ W_in,
    const float* __restrict__ carry, const float* __restrict__ wm_state,
    const float* __restrict__ xout,
    u16* __restrict__ wm_bf, u16* __restrict__ cur_bf)
{
  const int tid = threadIdx.x, quad = tid >> 4, l16 = tid & 15;
  const int m = blockIdx.x & 3;
  const int nt = blockIdx.x >> 2;
  const bool isAlpha = nt < 64;
  const int n0 = (isAlpha ? nt : nt - 64) * 16;
  ACC_DECL(1)
  wave_gemm<4, 1, DIM, false>(x_bf + (long)m * 64 * DIM, DIM,
                              (isAlpha ? W_alpha : W_in) + (long)n0 * DIM, DIM, 0, acc);
#pragma unroll
  for (int mi = 0; mi < 4; ++mi) {
    int n = n0 + l16;
#pragma unroll
    for (int r = 0; r < 4; ++r) {
      int s = m * 64 + mi * 16 + quad * 4 + r;
      float c = acc[mi][0][r];
      long idx = (long)s * DIM + n;
      if (isAlpha) wm_bf[idx] = f2bf(carry[s] * sigm(c) * wm_state[idx] + xout[idx]);
      else         cur_bf[idx] = f2bf(c);
    }
  }
}

// ---------------------------------------------------------------------------
// K3: y_wm = tanh(wm_new @ W_wm_out^T)   (256 blocks x 64 threads)
// ---------------------------------------------------------------------------
__global__ __launch_bounds__(64) void k_gemm2(
    const u16* __restrict__ wm_bf, const float* __restrict__ W_wm_out,
    float* __restrict__ yout, u16* __restrict__ ywm_bf)
{
  const int tid = threadIdx.x, quad = tid >> 4, l16 = tid & 15;
  const int m = blockIdx.x & 3;
  const int n0 = (blockIdx.x >> 2) * 16;
  ACC_DECL(1)
  wave_gemm<4, 1, DIM, false>(wm_bf + (long)m * 64 * DIM, DIM,
                              W_wm_out + (long)n0 * DIM, DIM, 0, acc);
#pragma unroll
  for (int mi = 0; mi < 4; ++mi) {
    int n = n0 + l16;
#pragma unroll
    for (int r = 0; r < 4; ++r) {
      int s = m * 64 + mi * 16 + quad * 4 + r;
      float y = tanhf(acc[mi][0][r]);
      long idx = (long)s * DIM + n;
      yout[idx] = y;
      ywm_bf[idx] = f2bf(y);
    }
  }
}

// ---------------------------------------------------------------------------
// K4/K6: a = cur@W_x^T + h@W_h^T + y_wm@W_wml^T
// 256 blocks x 64 threads: m = blk&3, nt = blk>>2 (64 e-tiles: b = nt>>3)
// ---------------------------------------------------------------------------
__global__ __launch_bounds__(64) void k_gemm_a(
    int l, const u16* __restrict__ cur_bf, const u16* __restrict__ h_bf,
    const u16* __restrict__ ywm_bf,
    const float* __restrict__ W_x, const float* __restrict__ W_h,
    const float* __restrict__ W_wml,
    float* __restrict__ a_f32, u16* __restrict__ a_bf)
{
  const int tid = threadIdx.x, quad = tid >> 4, l16 = tid & 15;
  const int m = blockIdx.x & 3;
  const int nt = blockIdx.x >> 2;
  const int b = nt >> 3;
  const int e0 = (nt & 7) * 16;
  ACC_DECL(1)
  const long moff = (long)m * 64 * DIM;
  wave_gemm<4, 1, DH, false>(cur_bf + moff + b * DH, DIM,
                             W_x + ((long)(l * NB + b) * DH + e0) * DH, DH, 0, acc);
  wave_gemm<4, 1, DH, false>(h_bf + (long)l * BSZ * DIM + moff + b * DH, DIM,
                             W_h + ((long)(l * NB + b) * DH + e0) * DH, DH, 0, acc);
  wave_gemm<4, 1, DIM, false>(ywm_bf + moff, DIM,
                              W_wml + ((long)(l * NB + b) * DH + e0) * DIM, DIM, 0, acc);
#pragma unroll
  for (int mi = 0; mi < 4; ++mi) {
    int e = e0 + l16;
#pragma unroll
    for (int r = 0; r < 4; ++r) {
      int s = m * 64 + mi * 16 + quad * 4 + r;
      float c = acc[mi][0][r];
      long idx = (long)s * DIM + b * DH + e;
      a_f32[idx] = c;
      a_bf[idx] = f2bf(c);
    }
  }
}

// ---------------------------------------------------------------------------
// K5/K7: g = sigmoid(a@W_g^T + surprise*w_s + b_g); h_new gating
// ---------------------------------------------------------------------------
__global__ __launch_bounds__(64) void k_gemm_g(
    int l, const u16* __restrict__ a_bf, const float* __restrict__ W_g,
    const float* __restrict__ w_s, const float* __restrict__ b_g,
    const float* __restrict__ surprise, const float* __restrict__ carry,
    const float* __restrict__ hstate, const float* __restrict__ a_f32,
    u16* __restrict__ hout_bf)
{
  const int tid = threadIdx.x, quad = tid >> 4, l16 = tid & 15;
  const int m = blockIdx.x & 3;
  const int nt = blockIdx.x >> 2;
  const int b = nt >> 3;
  const int e0 = (nt & 7) * 16;
  ACC_DECL(1)
  wave_gemm<4, 1, DH, false>(a_bf + (long)m * 64 * DIM + b * DH, DIM,
                             W_g + ((long)(l * NB + b) * DH + e0) * DH, DH, 0, acc);
#pragma unroll
  for (int mi = 0; mi < 4; ++mi) {
    int e = e0 + l16;
#pragma unroll
    for (int r = 0; r < 4; ++r) {
      int s = m * 64 + mi * 16 + quad * 4 + r;
      float c = acc[mi][0][r];
      long idx = (long)s * DIM + b * DH + e;
      float gp = c + surprise[s] * w_s[(l * NB + b) * DH + e] + b_g[(l * NB + b) * DH + e];
      float g = sigm(gp);
      float ho = hstate[(long)l * BSZ * DIM + idx];
      float hn = carry[s] * ((1.0f - g) * ho + g * tanhf(a_f32[idx]));
      hout_bf[idx] = f2bf(hn);
    }
  }
}

// ---------------------------------------------------------------------------
// K8: logits = h_final @ emb^T  — LDS-staged, T14 async-split pipeline.
// 1571 blocks x 256 threads (4 waves). Per block: all 256 rows x 32 vocab
// cols. B tile (32 x 64 K, fp32) staged global->reg->(f2bf)->LDS once per
// block (shared by 4 waves, converted once), double-buffered (8 KB LDS).
// XOR swizzle (byte ^= (row&7)<<4) keeps ds_write_b128/ds_read_b128 at the
// bank floor (linear [32][128B] layout would serialize all 16 lanes of a
// quad on bank 0). Next tile's global loads are issued BEFORE the MFMA
// phase and consumed after it: HBM/L3 latency hides under compute.
// ---------------------------------------------------------------------------
__global__ __launch_bounds__(256) void k_logits_lds(
    const u16* __restrict__ hfin_bf, const float* __restrict__ emb,
    float* __restrict__ out)
{
  __shared__ u16 Bs[2][32 * 64];          // 2 x 4 KB bf16 tiles
  const int tid  = threadIdx.x;
  const int wave = tid >> 6;
  const int lane = tid & 63;
  const int quad = lane >> 4;
  const int l16  = lane & 15;
  const int n0   = blockIdx.x * 32;

  // --- staging map: thread -> (row 0..31, k-elems scol..scol+7) ---
  const int srow = tid >> 3;              // 0..31
  const int scol = (tid & 7) * 8;         // 0,8,...,56
  long gn = n0 + srow;
  if (gn >= VOC) gn = VOC - 1;            // tail clamp; dup values discarded on store
  const float* src = emb + gn * DIM + scol;
  const int sbyte = srow * 128 + ((scol * 2) ^ ((srow & 7) << 4));

  // --- A fragment pointers (hfin_bf is L2-resident, 512 KB) ---
  const u16* aP[4];
#pragma unroll
  for (int mi = 0; mi < 4; ++mi)
    aP[mi] = hfin_bf + (long)(wave * 64 + mi * 16 + l16) * DIM + quad * 8;

  f32x4 acc[4][2];
  { f32x4 z = {0.f, 0.f, 0.f, 0.f};
#pragma unroll
    for (int mi = 0; mi < 4; ++mi)
#pragma unroll
      for (int ni = 0; ni < 2; ++ni) acc[mi][ni] = z; }

#define CVT_WRITE(dstbase)                                                \
  {                                                                       \
    u16x8 h8;                                                             \
    h8[0] = f2bf(pA.x); h8[1] = f2bf(pA.y);                               \
    h8[2] = f2bf(pA.z); h8[3] = f2bf(pA.w);                               \
    h8[4] = f2bf(pB.x); h8[5] = f2bf(pB.y);                               \
    h8[6] = f2bf(pB.z); h8[7] = f2bf(pB.w);                               \
    *(u16x8*)((char*)(dstbase) + sbyte) = h8;                             \
  }

  float4 pA, pB;
  // prologue: tile 0 -> LDS buf 0; preload tile 1 into regs
  pA = *(const float4*)(src);
  pB = *(const float4*)(src + 4);
  CVT_WRITE(&Bs[0][0])
  pA = *(const float4*)(src + 64);
  pB = *(const float4*)(src + 68);
  __syncthreads();

  const int NT = DIM / 64;                // 16
#pragma unroll 1
  for (int t = 0; t < NT; ++t) {
    const char* bb = (const char*)&Bs[t & 1][0];
    const int k0 = t * 64;

    bf16x8 aF0[4], aF1[4], bF0[2], bF1[2];
#pragma unroll
    for (int mi = 0; mi < 4; ++mi) aF0[mi] = *(const bf16x8*)(aP[mi] + k0);
#pragma unroll
    for (int mi = 0; mi < 4; ++mi) aF1[mi] = *(const bf16x8*)(aP[mi] + k0 + 32);
#pragma unroll
    for (int ni = 0; ni < 2; ++ni) {
      const int row = ni * 16 + l16;
      const int ib0 = (quad * 16) ^ ((row & 7) << 4);
      bF0[ni] = *(const bf16x8*)(bb + row * 128 + ib0);
      bF1[ni] = *(const bf16x8*)(bb + row * 128 + (ib0 ^ 64));
    }
#pragma unroll
    for (int mi = 0; mi < 4; ++mi)
#pragma unroll
      for (int ni = 0; ni < 2; ++ni)
        acc[mi][ni] = __builtin_amdgcn_mfma_f32_16x16x32_bf16(
            aF0[mi], bF0[ni], acc[mi][ni], 0, 0, 0);
#pragma unroll
    for (int mi = 0; mi < 4; ++mi)
#pragma unroll
      for (int ni = 0; ni < 2; ++ni)
        acc[mi][ni] = __builtin_amdgcn_mfma_f32_16x16x32_bf16(
            aF1[mi], bF1[ni], acc[mi][ni], 0, 0, 0);

    __syncthreads();                      // all waves done reading Bs[t&1]
    if (t + 1 < NT) {
      // pre-loaded regs for tile t+1 arrive here (hidden under MFMAs)
      CVT_WRITE(&Bs[(t + 1) & 1][0])
      if (t + 2 < NT) {
        pA = *(const float4*)(src + (t + 2) * 64);
        pB = *(const float4*)(src + (t + 2) * 64 + 4);
      }
    }
    __syncthreads();                      // write visible before next compute
  }
#undef CVT_WRITE

#pragma unroll
  for (int mi = 0; mi < 4; ++mi)
#pragma unroll
    for (int ni = 0; ni < 2; ++ni) {
      int n = n0 + ni * 16 + l16;
      if (n < VOC) {
#pragma unroll
        for (int r = 0; r < 4; ++r) {
          int s = wave * 64 + mi * 16 + quad * 4 + r;
          out[(long)s * VOC + n] = acc[mi][ni][r];
        }
      }
    }
}

extern "C" void kernel_launch(void* const* d_in, const int* in_sizes, int n_in,
                              void* d_out, int out_size, void* d_ws, size_t ws_size,
                              hipStream_t stream) {
  const int*   input_id = (const int*)d_in[0];
  const void*  reset    = d_in[1];
  const float* surprise = (const float*)d_in[2];
  const float* wm_state = (const float*)d_in[3];
  const float* h_state  = (const float*)d_in[4];
  const float* emb      = (const float*)d_in[5];
  const float* W_in     = (const float*)d_in[6];
  const float* W_alpha  = (const float*)d_in[7];
  const float* W_wm_out = (const float*)d_in[8];
  const float* W_x      = (const float*)d_in[9];
  const float* W_h      = (const float*)d_in[10];
  const float* W_wml    = (const float*)d_in[11];
  const float* W_g      = (const float*)d_in[12];
  const float* w_s      = (const float*)d_in[13];
  const float* b_g      = (const float*)d_in[14];

  float* out  = (float*)d_out;
  float* xout = out + (size_t)BSZ * VOC;          // x output (fp32, exact)
  float* yout = xout + (size_t)BSZ * DIM;         // y_wm output

  // Scratch lives in the logits region of d_out (only read before k_logits).
  const long SD = (long)BSZ * DIM;                // 262144
  u16* scr    = (u16*)d_out;
  u16* x_bf   = scr;                              // 256x1024
  u16* wm_bf  = scr + SD;
  u16* cur_bf = scr + 2 * SD;
  u16* ywm_bf = scr + 3 * SD;
  u16* h_bf   = scr + 4 * SD;                     // 2x256x1024
  u16* a_bf   = scr + 6 * SD;
  float* a_f32 = (float*)(scr + 8 * SD);          // 256x1024 fp32

  // h_final + carry live OUTSIDE d_out (read while k_logits writes d_out)
  float* carry  = (float*)d_ws;
  u16* hfin_bf  = (u16*)((char*)d_ws + 1024);
  float* sink   = (float*)((char*)d_ws + 600 * 1024);

  k_prep<<<BSZ, 256, 0, stream>>>(input_id, reset, emb, h_state,
                                  W_alpha, W_in, W_wm_out, W_x, W_h, W_wml, W_g,
                                  xout, x_bf, h_bf, carry, sink);
  k_gemm1<<<512, 64, 0, stream>>>(x_bf, W_alpha, W_in, carry, wm_state, xout, wm_bf, cur_bf);
  k_gemm2<<<256, 64, 0, stream>>>(wm_bf, W_wm_out, yout, ywm_bf);
  k_gemm_a<<<256, 64, 0, stream>>>(0, cur_bf, h_bf, ywm_bf, W_x, W_h, W_wml, a_f32, a_bf);
  k_gemm_g<<<256, 64, 0, stream>>>(0, a_bf, W_g, w_s, b_g, surprise, carry, h_state, a_f32, cur_bf);
  k_gemm_a<<<256, 64, 0, stream>>>(1, cur_bf, h_bf, ywm_bf, W_x, W_h, W_wml, a_f32, a_bf);
  k_gemm_g<<<256, 64, 0, stream>>>(1, a_bf, W_g, w_s, b_g, surprise, carry, h_state, a_f32, hfin_bf);
  k_logits_lds<<<(VOC + 31) / 32, 256, 0, stream>>>(hfin_bf, emb, out);
}

// Round 2
// 461.125 us; speedup vs baseline: 1.2803x; 1.0948x over previous
//
#include <hip/hip_runtime.h>
#include <math.h>

#define BSZ 256
#define DIM 1024
#define VOC 50257
#define NL 2
#define NB 8
#define DH 128

typedef __bf16 bf16x8 __attribute__((ext_vector_type(8)));
typedef float  f32x4  __attribute__((ext_vector_type(4)));
typedef unsigned short u16;
typedef u16 u16x8 __attribute__((ext_vector_type(8)));

__device__ __forceinline__ u16 f2bf(float f) {
  unsigned int u = __float_as_uint(f);
  u += 0x7fffu + ((u >> 16) & 1u);   // RNE
  return (u16)(u >> 16);
}
__device__ __forceinline__ float sigm(float x) { return 1.0f / (1.0f + __expf(-x)); }

// ---------------------------------------------------------------------------
// Barrier-free per-wave GEMM: acc[M16][N16] += A(bf16, row-major lda) *
// B(fp32, row-major ldb)^T. Fragments loaded directly from global in MFMA
// operand layout. 4-stage register pipeline (statically-indexed buffers,
// unroll-4 body): ~2x the in-flight loads of the old 2-stage version, to
// halve exposed cache latency in the 1-2 wave/CU regime the middle kernels
// run in. Requires K % 128 == 0 (all uses are K=128 or K=1024).
// ---------------------------------------------------------------------------
template<int M16, int N16, int K, bool CLAMPN>
__device__ __forceinline__ void wave_gemm(
    const u16* __restrict__ A, int lda,
    const float* __restrict__ B, int ldb, int nClamp,
    f32x4 (&acc)[M16][N16])
{
  const int lane = threadIdx.x & 63;
  const int quad = lane >> 4;
  const int l16  = lane & 15;

  const u16* aR[M16];
  const float* bR[N16];
#pragma unroll
  for (int mi = 0; mi < M16; ++mi)
    aR[mi] = A + (long)(mi * 16 + l16) * lda + quad * 8;
#pragma unroll
  for (int ni = 0; ni < N16; ++ni) {
    int n = ni * 16 + l16;
    if (CLAMPN) n = n > nClamp ? nClamp : n;   // clamp addr; result discarded
    bR[ni] = B + (long)n * ldb + quad * 8;
  }

  bf16x8 aF[4][M16];
  bf16x8 bF[4][N16];

#define WG_LOAD(kk, buf)                                                  \
  {                                                                       \
    _Pragma("unroll")                                                     \
    for (int ni = 0; ni < N16; ++ni) {                                    \
      float4 v0 = *(const float4*)(bR[ni] + (kk));                        \
      float4 v1 = *(const float4*)(bR[ni] + (kk) + 4);                    \
      u16x8 h;                                                            \
      h[0] = f2bf(v0.x); h[1] = f2bf(v0.y);                               \
      h[2] = f2bf(v0.z); h[3] = f2bf(v0.w);                               \
      h[4] = f2bf(v1.x); h[5] = f2bf(v1.y);                               \
      h[6] = f2bf(v1.z); h[7] = f2bf(v1.w);                               \
      bF[buf][ni] = __builtin_bit_cast(bf16x8, h);                        \
    }                                                                     \
    _Pragma("unroll")                                                     \
    for (int mi = 0; mi < M16; ++mi)                                      \
      aF[buf][mi] = *(const bf16x8*)(aR[mi] + (kk));                      \
  }

#define WG_MM(buf)                                                        \
  {                                                                       \
    _Pragma("unroll")                                                     \
    for (int mi = 0; mi < M16; ++mi)                                      \
      _Pragma("unroll")                                                   \
      for (int ni = 0; ni < N16; ++ni)                                    \
        acc[mi][ni] = __builtin_amdgcn_mfma_f32_16x16x32_bf16(            \
            aF[buf][mi], bF[buf][ni], acc[mi][ni], 0, 0, 0);              \
  }

  WG_LOAD(0, 0);
  WG_LOAD(32, 1);
  WG_LOAD(64, 2);
#pragma unroll 1
  for (int kk = 0; kk < K - 128; kk += 128) {
    WG_LOAD(kk + 96, 3);  WG_MM(0);
    WG_LOAD(kk + 128, 0); WG_MM(1);
    WG_LOAD(kk + 160, 1); WG_MM(2);
    WG_LOAD(kk + 192, 2); WG_MM(3);
  }
  WG_LOAD(K - 32, 3);
  WG_MM(0); WG_MM(1); WG_MM(2); WG_MM(3);
#undef WG_LOAD
#undef WG_MM
}

#define ACC_DECL(N16V)                                \
  f32x4 acc[4][N16V];                                 \
  { f32x4 z = {0.f, 0.f, 0.f, 0.f};                   \
    _Pragma("unroll")                                 \
    for (int i = 0; i < 4; ++i)                       \
      _Pragma("unroll")                               \
      for (int j = 0; j < N16V; ++j) acc[i][j] = z; }

// ---------------------------------------------------------------------------
// K1: carry (bool-layout detect), x gather, h->bf16, + LLC warm of all weights
// ---------------------------------------------------------------------------
__global__ __launch_bounds__(256) void k_prep(
    const int* __restrict__ ids, const void* __restrict__ mask,
    const float* __restrict__ emb, const float* __restrict__ hstate,
    const float* __restrict__ W_alpha, const float* __restrict__ W_in,
    const float* __restrict__ W_wm_out, const float* __restrict__ W_x,
    const float* __restrict__ W_h, const float* __restrict__ W_wml,
    const float* __restrict__ W_g,
    float* __restrict__ xout, u16* __restrict__ x_bf,
    u16* __restrict__ h_bf, float* __restrict__ carry, float* __restrict__ sink)
{
  __shared__ int sInt;
  const int tid = threadIdx.x, s = blockIdx.x;
  if (tid == 0) sInt = 1;
  __syncthreads();
  if (tid < 64) {
    int v = ((const int*)mask)[tid];
    if (v != 0 && v != 1) atomicAnd(&sInt, 0);
  }
  __syncthreads();
  if (tid == 0) {
    int m = sInt ? ((const int*)mask)[s] : (int)((const unsigned char*)mask)[s];
    carry[s] = m ? 0.0f : 1.0f;
  }
  long id = ids[s];
  int k = tid * 4;
  float4 v = *(const float4*)(emb + id * DIM + k);
  *(float4*)(xout + (long)s * DIM + k) = v;
  ushort4 h; h.x = f2bf(v.x); h.y = f2bf(v.y); h.z = f2bf(v.z); h.w = f2bf(v.w);
  *(ushort4*)(x_bf + (long)s * DIM + k) = h;
#pragma unroll
  for (int l = 0; l < NL; ++l) {
    long off = (long)l * BSZ * DIM + (long)s * DIM + k;
    float4 w = *(const float4*)(hstate + off);
    ushort4 o; o.x = f2bf(w.x); o.y = f2bf(w.y); o.z = f2bf(w.z); o.w = f2bf(w.w);
    *(ushort4*)(h_bf + off) = o;
  }
  // ---- LLC warm (loads can't be eliminated; branch never taken) ----
  long gtid = (long)blockIdx.x * 256 + tid;
  long gstride = (long)gridDim.x * 256;
  float acc = 0.f;
  {
    const long nDD = (long)DIM * DIM / 4;       // 1024x1024 f32 -> float4 count
    for (long i = gtid; i < nDD; i += gstride) {
      float4 a = ((const float4*)W_alpha)[i];
      float4 b = ((const float4*)W_in)[i];
      float4 c = ((const float4*)W_wm_out)[i];
      acc += a.x + a.w + b.x + b.w + c.x + c.w;
    }
    const long nS = (long)NL * NB * DH * DH / 4;
    for (long i = gtid; i < nS; i += gstride) {
      float4 a = ((const float4*)W_x)[i];
      float4 b = ((const float4*)W_h)[i];
      float4 c = ((const float4*)W_g)[i];
      acc += a.x + a.w + b.x + b.w + c.x + c.w;
    }
    const long nW = (long)NL * NB * DH * DIM / 4;
    for (long i = gtid; i < nW; i += gstride) {
      float4 a = ((const float4*)W_wml)[i];
      acc += a.x + a.w;
    }
  }
  if (acc == -1.17521e35f) *sink = acc;   // never true in practice; defeats DCE
}

// ---------------------------------------------------------------------------
// K2: [alpha_pre | x_proj] = x @ [W_alpha ; W_in]^T, fused wm_new epilogue
// 512 blocks x 64 threads: m-slice = blk&3, n-tile16 = blk>>2 (128 tiles)
// ---------------------------------------------------------------------------
__global__ __launch_bounds__(64) void k_gemm1(
    const u16* __restrict__ x_bf,
    const float* __restrict__ W_alpha, const float* __restrict__ W_in,
    const float* __restrict__ carry, const float* __restrict__ wm_state,
    const float* __restrict__ xout,
    u16* __restrict__ wm_bf, u16* __restrict__ cur_bf)
{
  const int tid = threadIdx.x, quad = tid >> 4, l16 = tid & 15;
  const int m = blockIdx.x & 3;
  const int nt = blockIdx.x >> 2;
  const bool isAlpha = nt < 64;
  const int n0 = (isAlpha ? nt : nt - 64) * 16;
  ACC_DECL(1)
  wave_gemm<4, 1, DIM, false>(x_bf + (long)m * 64 * DIM, DIM,
                              (isAlpha ? W_alpha : W_in) + (long)n0 * DIM, DIM, 0, acc);
#pragma unroll
  for (int mi = 0; mi < 4; ++mi) {
    int n = n0 + l16;
#pragma unroll
    for (int r = 0; r < 4; ++r) {
      int s = m * 64 + mi * 16 + quad * 4 + r;
      float c = acc[mi][0][r];
      long idx = (long)s * DIM + n;
      if (isAlpha) wm_bf[idx] = f2bf(carry[s] * sigm(c) * wm_state[idx] + xout[idx]);
      else         cur_bf[idx] = f2bf(c);
    }
  }
}

// ---------------------------------------------------------------------------
// K3: y_wm = tanh(wm_new @ W_wm_out^T)   (256 blocks x 64 threads)
// ---------------------------------------------------------------------------
__global__ __launch_bounds__(64) void k_gemm2(
    const u16* __restrict__ wm_bf, const float* __restrict__ W_wm_out,
    float* __restrict__ yout, u16* __restrict__ ywm_bf)
{
  const int tid = threadIdx.x, quad = tid >> 4, l16 = tid & 15;
  const int m = blockIdx.x & 3;
  const int n0 = (blockIdx.x >> 2) * 16;
  ACC_DECL(1)
  wave_gemm<4, 1, DIM, false>(wm_bf + (long)m * 64 * DIM, DIM,
                              W_wm_out + (long)n0 * DIM, DIM, 0, acc);
#pragma unroll
  for (int mi = 0; mi < 4; ++mi) {
    int n = n0 + l16;
#pragma unroll
    for (int r = 0; r < 4; ++r) {
      int s = m * 64 + mi * 16 + quad * 4 + r;
      float y = tanhf(acc[mi][0][r]);
      long idx = (long)s * DIM + n;
      yout[idx] = y;
      ywm_bf[idx] = f2bf(y);
    }
  }
}

// ---------------------------------------------------------------------------
// K4/K6: a = cur@W_x^T + h@W_h^T + y_wm@W_wml^T
// 256 blocks x 64 threads: m = blk&3, nt = blk>>2 (64 e-tiles: b = nt>>3)
// ---------------------------------------------------------------------------
__global__ __launch_bounds__(64) void k_gemm_a(
    int l, const u16* __restrict__ cur_bf, const u16* __restrict__ h_bf,
    const u16* __restrict__ ywm_bf,
    const float* __restrict__ W_x, const float* __restrict__ W_h,
    const float* __restrict__ W_wml,
    float* __restrict__ a_f32, u16* __restrict__ a_bf)
{
  const int tid = threadIdx.x, quad = tid >> 4, l16 = tid & 15;
  const int m = blockIdx.x & 3;
  const int nt = blockIdx.x >> 2;
  const int b = nt >> 3;
  const int e0 = (nt & 7) * 16;
  ACC_DECL(1)
  const long moff = (long)m * 64 * DIM;
  wave_gemm<4, 1, DH, false>(cur_bf + moff + b * DH, DIM,
                             W_x + ((long)(l * NB + b) * DH + e0) * DH, DH, 0, acc);
  wave_gemm<4, 1, DH, false>(h_bf + (long)l * BSZ * DIM + moff + b * DH, DIM,
                             W_h + ((long)(l * NB + b) * DH + e0) * DH, DH, 0, acc);
  wave_gemm<4, 1, DIM, false>(ywm_bf + moff, DIM,
                              W_wml + ((long)(l * NB + b) * DH + e0) * DIM, DIM, 0, acc);
#pragma unroll
  for (int mi = 0; mi < 4; ++mi) {
    int e = e0 + l16;
#pragma unroll
    for (int r = 0; r < 4; ++r) {
      int s = m * 64 + mi * 16 + quad * 4 + r;
      float c = acc[mi][0][r];
      long idx = (long)s * DIM + b * DH + e;
      a_f32[idx] = c;
      a_bf[idx] = f2bf(c);
    }
  }
}

// ---------------------------------------------------------------------------
// K5/K7: g = sigmoid(a@W_g^T + surprise*w_s + b_g); h_new gating
// ---------------------------------------------------------------------------
__global__ __launch_bounds__(64) void k_gemm_g(
    int l, const u16* __restrict__ a_bf, const float* __restrict__ W_g,
    const float* __restrict__ w_s, const float* __restrict__ b_g,
    const float* __restrict__ surprise, const float* __restrict__ carry,
    const float* __restrict__ hstate, const float* __restrict__ a_f32,
    u16* __restrict__ hout_bf)
{
  const int tid = threadIdx.x, quad = tid >> 4, l16 = tid & 15;
  const int m = blockIdx.x & 3;
  const int nt = blockIdx.x >> 2;
  const int b = nt >> 3;
  const int e0 = (nt & 7) * 16;
  ACC_DECL(1)
  wave_gemm<4, 1, DH, false>(a_bf + (long)m * 64 * DIM + b * DH, DIM,
                             W_g + ((long)(l * NB + b) * DH + e0) * DH, DH, 0, acc);
#pragma unroll
  for (int mi = 0; mi < 4; ++mi) {
    int e = e0 + l16;
#pragma unroll
    for (int r = 0; r < 4; ++r) {
      int s = m * 64 + mi * 16 + quad * 4 + r;
      float c = acc[mi][0][r];
      long idx = (long)s * DIM + b * DH + e;
      float gp = c + surprise[s] * w_s[(l * NB + b) * DH + e] + b_g[(l * NB + b) * DH + e];
      float g = sigm(gp);
      float ho = hstate[(long)l * BSZ * DIM + idx];
      float hn = carry[s] * ((1.0f - g) * ho + g * tanhf(a_f32[idx]));
      hout_bf[idx] = f2bf(hn);
    }
  }
}

// ---------------------------------------------------------------------------
// K8: logits = h_final @ emb^T — LDS-staged, single barrier per K-tile.
// 786 blocks x 256 threads (4 waves). Per block: all 256 batch rows x 64
// vocab cols (halves the redundant A-traffic vs 32-col tiles and doubles
// MFMA work per barrier). B tile (64 rows x 64 K, fp32) staged
// global->reg->(f2bf)->LDS, double-buffered (16 KB LDS), XOR-swizzled.
//
// ONE barrier per tile: at iter t each wave reads buf[t&1] and writes
// buf[(t+1)&1]. buf[(t+1)&1] was last READ at iter t-1, and every wave's
// reads complete before its end-of-(t-1) barrier (syncthreads drains
// lgkmcnt), so the write is race-free. Stage loads are issued 2 tiles
// ahead (one full MFMA phase + barrier of latency cover).
// ---------------------------------------------------------------------------
__global__ __launch_bounds__(256) void k_logits_lds(
    const u16* __restrict__ hfin_bf, const float* __restrict__ emb,
    float* __restrict__ out)
{
  __shared__ u16 Bs[2][64 * 64];          // 2 x 8 KB bf16 tiles
  const int tid  = threadIdx.x;
  const int wave = tid >> 6;
  const int lane = tid & 63;
  const int quad = lane >> 4;
  const int l16  = lane & 15;
  const int n0   = blockIdx.x * 64;

  // --- staging map: thread -> (row 0..63, 16 f32 at col scol..scol+15) ---
  const int srow = tid >> 2;              // 0..63
  const int scol = (tid & 3) * 16;        // f32 col: 0,16,32,48
  long gn = n0 + srow;
  if (gn >= VOC) gn = VOC - 1;            // tail clamp; dup values discarded on store
  const float* src = emb + gn * DIM + scol;
  const int sw  = (srow & 7) << 4;
  const int sb0 = srow * 128 + ((scol * 2) ^ sw);
  const int sb1 = srow * 128 + (((scol * 2) + 16) ^ sw);

  // --- A fragment pointers (hfin_bf is 512 KB, L2-resident in every XCD) ---
  const u16* aP[4];
#pragma unroll
  for (int mi = 0; mi < 4; ++mi)
    aP[mi] = hfin_bf + (long)(wave * 64 + mi * 16 + l16) * DIM + quad * 8;

  f32x4 acc[4][4];
  { f32x4 z = {0.f, 0.f, 0.f, 0.f};
#pragma unroll
    for (int mi = 0; mi < 4; ++mi)
#pragma unroll
      for (int ni = 0; ni < 4; ++ni) acc[mi][ni] = z; }

  float4 pA, pB, pC, pD;
#define LD4(t)                                                            \
  { pA = *(const float4*)(src + (t) * 64);                                \
    pB = *(const float4*)(src + (t) * 64 + 4);                            \
    pC = *(const float4*)(src + (t) * 64 + 8);                            \
    pD = *(const float4*)(src + (t) * 64 + 12); }
#define CVT_WR(bufi)                                                      \
  { u16x8 h0, h1;                                                         \
    h0[0] = f2bf(pA.x); h0[1] = f2bf(pA.y);                               \
    h0[2] = f2bf(pA.z); h0[3] = f2bf(pA.w);                               \
    h0[4] = f2bf(pB.x); h0[5] = f2bf(pB.y);                               \
    h0[6] = f2bf(pB.z); h0[7] = f2bf(pB.w);                               \
    h1[0] = f2bf(pC.x); h1[1] = f2bf(pC.y);                               \
    h1[2] = f2bf(pC.z); h1[3] = f2bf(pC.w);                               \
    h1[4] = f2bf(pD.x); h1[5] = f2bf(pD.y);                               \
    h1[6] = f2bf(pD.z); h1[7] = f2bf(pD.w);                               \
    *(u16x8*)((char*)&Bs[bufi][0] + sb0) = h0;                            \
    *(u16x8*)((char*)&Bs[bufi][0] + sb1) = h1; }

  // prologue: tile 0 -> LDS buf 0; tile 1 into regs
  LD4(0)
  CVT_WR(0)
  LD4(1)
  __syncthreads();

  const int NT = DIM / 64;                // 16
#pragma unroll 1
  for (int t = 0; t < NT; ++t) {
    const char* bb = (const char*)&Bs[t & 1][0];
    const int k0 = t * 64;

    bf16x8 aF0[4], aF1[4], bF0[4], bF1[4];
#pragma unroll
    for (int mi = 0; mi < 4; ++mi) aF0[mi] = *(const bf16x8*)(aP[mi] + k0);
#pragma unroll
    for (int mi = 0; mi < 4; ++mi) aF1[mi] = *(const bf16x8*)(aP[mi] + k0 + 32);
#pragma unroll
    for (int ni = 0; ni < 4; ++ni) {
      const int row = ni * 16 + l16;
      const int ib0 = (quad * 16) ^ ((row & 7) << 4);
      bF0[ni] = *(const bf16x8*)(bb + row * 128 + ib0);
      bF1[ni] = *(const bf16x8*)(bb + row * 128 + (ib0 ^ 64));
    }
#pragma unroll
    for (int mi = 0; mi < 4; ++mi)
#pragma unroll
      for (int ni = 0; ni < 4; ++ni)
        acc[mi][ni] = __builtin_amdgcn_mfma_f32_16x16x32_bf16(
            aF0[mi], bF0[ni], acc[mi][ni], 0, 0, 0);
#pragma unroll
    for (int mi = 0; mi < 4; ++mi)
#pragma unroll
      for (int ni = 0; ni < 4; ++ni)
        acc[mi][ni] = __builtin_amdgcn_mfma_f32_16x16x32_bf16(
            aF1[mi], bF1[ni], acc[mi][ni], 0, 0, 0);

    if (t + 1 < NT) {
      CVT_WR((t + 1) & 1)                 // regs(t+1) landed during tile t
      if (t + 2 < NT) LD4(t + 2)          // issue next loads before barrier
    }
    __syncthreads();                      // single barrier per tile
  }
#undef LD4
#undef CVT_WR

#pragma unroll
  for (int mi = 0; mi < 4; ++mi)
#pragma unroll
    for (int ni = 0; ni < 4; ++ni) {
      int n = n0 + ni * 16 + l16;
      if (n < VOC) {
#pragma unroll
        for (int r = 0; r < 4; ++r) {
          int s = wave * 64 + mi * 16 + quad * 4 + r;
          out[(long)s * VOC + n] = acc[mi][ni][r];
        }
      }
    }
}

extern "C" void kernel_launch(void* const* d_in, const int* in_sizes, int n_in,
                              void* d_out, int out_size, void* d_ws, size_t ws_size,
                              hipStream_t stream) {
  const int*   input_id = (const int*)d_in[0];
  const void*  reset    = d_in[1];
  const float* surprise = (const float*)d_in[2];
  const float* wm_state = (const float*)d_in[3];
  const float* h_state  = (const float*)d_in[4];
  const float* emb      = (const float*)d_in[5];
  const float* W_in     = (const float*)d_in[6];
  const float* W_alpha  = (const float*)d_in[7];
  const float* W_wm_out = (const float*)d_in[8];
  const float* W_x      = (const float*)d_in[9];
  const float* W_h      = (const float*)d_in[10];
  const float* W_wml    = (const float*)d_in[11];
  const float* W_g      = (const float*)d_in[12];
  const float* w_s      = (const float*)d_in[13];
  const float* b_g      = (const float*)d_in[14];

  float* out  = (float*)d_out;
  float* xout = out + (size_t)BSZ * VOC;          // x output (fp32, exact)
  float* yout = xout + (size_t)BSZ * DIM;         // y_wm output

  // Scratch lives in the logits region of d_out (only read before k_logits).
  const long SD = (long)BSZ * DIM;                // 262144
  u16* scr    = (u16*)d_out;
  u16* x_bf   = scr;                              // 256x1024
  u16* wm_bf  = scr + SD;
  u16* cur_bf = scr + 2 * SD;
  u16* ywm_bf = scr + 3 * SD;
  u16* h_bf   = scr + 4 * SD;                     // 2x256x1024
  u16* a_bf   = scr + 6 * SD;
  float* a_f32 = (float*)(scr + 8 * SD);          // 256x1024 fp32

  // h_final + carry live OUTSIDE d_out (read while k_logits writes d_out)
  float* carry  = (float*)d_ws;
  u16* hfin_bf  = (u16*)((char*)d_ws + 1024);
  float* sink   = (float*)((char*)d_ws + 600 * 1024);

  k_prep<<<BSZ, 256, 0, stream>>>(input_id, reset, emb, h_state,
                                  W_alpha, W_in, W_wm_out, W_x, W_h, W_wml, W_g,
                                  xout, x_bf, h_bf, carry, sink);
  k_gemm1<<<512, 64, 0, stream>>>(x_bf, W_alpha, W_in, carry, wm_state, xout, wm_bf, cur_bf);
  k_gemm2<<<256, 64, 0, stream>>>(wm_bf, W_wm_out, yout, ywm_bf);
  k_gemm_a<<<256, 64, 0, stream>>>(0, cur_bf, h_bf, ywm_bf, W_x, W_h, W_wml, a_f32, a_bf);
  k_gemm_g<<<256, 64, 0, stream>>>(0, a_bf, W_g, w_s, b_g, surprise, carry, h_state, a_f32, cur_bf);
  k_gemm_a<<<256, 64, 0, stream>>>(1, cur_bf, h_bf, ywm_bf, W_x, W_h, W_wml, a_f32, a_bf);
  k_gemm_g<<<256, 64, 0, stream>>>(1, a_bf, W_g, w_s, b_g, surprise, carry, h_state, a_f32, hfin_bf);
  k_logits_lds<<<(VOC + 63) / 64, 256, 0, stream>>>(hfin_bf, emb, out);
}